// Round 3
// 501.804 us; speedup vs baseline: 1.0010x; 1.0010x over previous
//
#include <hip/hip_runtime.h>
#include <math.h>

#define ALPHA 0.2f
#define S_DIM 64
#define D_DIM 128
#define TILE_F4 2048   // 64*128/4 float4s per group per input

__global__ __launch_bounds__(256) void gat_fused_kernel(
    const float* __restrict__ center,
    const float* __restrict__ nbr,
    const float* __restrict__ a,
    float* __restrict__ out)
{
    const int n = blockIdx.x;        // group index
    const int t = threadIdx.x;       // 0..255
    const int c = t & 31;            // float4-chunk within a row (0..31)
    const int g = t >> 5;            // 0..7
    const int d0 = c * 4;            // starting feature index of my chunk

    __shared__ float e_lds[S_DIM];
    __shared__ float att_lds[S_DIM];
    __shared__ float out_lds[8 * D_DIM];   // per-g partial outputs

    const float4* c4p = (const float4*)(center + (size_t)n * (S_DIM * D_DIM));
    const float4* n4p = (const float4*)(nbr    + (size_t)n * (S_DIM * D_DIM));

    // a slices for my d-chunk (constant across k since (t+256k)%32 == t%32)
    const float4 a0 = *(const float4*)(a + d0);
    const float4 a1 = *(const float4*)(a + D_DIM + d0);

    // ---- Phase 1: stream both inputs once; nbr stays in registers ----
    float4 nv[8];
    float partial[8];
#pragma unroll
    for (int k = 0; k < 8; ++k) {
        const int f = t + 256 * k;       // flat float4 index; coalesced
        const float4 cv = c4p[f];
        const float4 nk = n4p[f];
        nv[k] = nk;
        partial[k] = cv.x * a0.x + cv.y * a0.y + cv.z * a0.z + cv.w * a0.w
                   + nk.x * a1.x + nk.y * a1.y + nk.z * a1.z + nk.w * a1.w;
    }

    // reduce each partial across its aligned 32-lane group -> e[s], s = g + 8k
#pragma unroll
    for (int k = 0; k < 8; ++k) {
        float v = partial[k];
        v += __shfl_xor(v, 16);
        v += __shfl_xor(v, 8);
        v += __shfl_xor(v, 4);
        v += __shfl_xor(v, 2);
        v += __shfl_xor(v, 1);
        if (c == 0) e_lds[g + 8 * k] = v;
    }
    __syncthreads();

    // ---- Softmax over S=64 by wave 0 ----
    if (t < 64) {
        float v = e_lds[t];
        v = (v > 0.0f) ? v : ALPHA * v;         // leaky_relu
        float m = v;
        m = fmaxf(m, __shfl_xor(m, 32));
        m = fmaxf(m, __shfl_xor(m, 16));
        m = fmaxf(m, __shfl_xor(m, 8));
        m = fmaxf(m, __shfl_xor(m, 4));
        m = fmaxf(m, __shfl_xor(m, 2));
        m = fmaxf(m, __shfl_xor(m, 1));
        const float ex = expf(v - m);
        float sum = ex;
        sum += __shfl_xor(sum, 32);
        sum += __shfl_xor(sum, 16);
        sum += __shfl_xor(sum, 8);
        sum += __shfl_xor(sum, 4);
        sum += __shfl_xor(sum, 2);
        sum += __shfl_xor(sum, 1);
        att_lds[t] = ex / sum;
    }
    __syncthreads();

    // ---- Phase 2: weighted sum of register-resident nbr chunks ----
    float4 o = make_float4(0.f, 0.f, 0.f, 0.f);
#pragma unroll
    for (int k = 0; k < 8; ++k) {
        const float w = att_lds[g + 8 * k];     // broadcast within 32-lane group
        o.x += w * nv[k].x;
        o.y += w * nv[k].y;
        o.z += w * nv[k].z;
        o.w += w * nv[k].w;
    }
    // each thread owns a unique (g, c) slot — no conflicts
    *(float4*)(out_lds + g * D_DIM + d0) = o;
    __syncthreads();

    // ---- Final cross-g reduction + coalesced store (32 lanes x float4) ----
    if (t < 32) {
        float4 s = make_float4(0.f, 0.f, 0.f, 0.f);
#pragma unroll
        for (int gg = 0; gg < 8; ++gg) {
            const float4 v = *(const float4*)(out_lds + gg * D_DIM + t * 4);
            s.x += v.x; s.y += v.y; s.z += v.z; s.w += v.w;
        }
        *(float4*)(out + (size_t)n * D_DIM + t * 4) = s;
    }
}

extern "C" void kernel_launch(void* const* d_in, const int* in_sizes, int n_in,
                              void* d_out, int out_size, void* d_ws, size_t ws_size,
                              hipStream_t stream) {
    const float* center = (const float*)d_in[0];
    const float* nbr    = (const float*)d_in[1];
    const float* a      = (const float*)d_in[2];
    float* out = (float*)d_out;

    // Unit-independent N: in_sizes[0]/in_sizes[2] = (N*S*D)/(2*D) = N*32
    // whether in_sizes reports elements or bytes (the unit cancels).
    // elements: 67108864/256/32 = 8192; bytes: 268435456/1024/32 = 8192.
    int N;
    if (n_in >= 3 && in_sizes[2] > 0) {
        N = (in_sizes[0] / in_sizes[2]) / 32;
    } else {
        N = in_sizes[0] / (S_DIM * D_DIM);   // legacy fallback (round-0 formula)
    }
    if (N < 1) N = 1;

    gat_fused_kernel<<<N, 256, 0, stream>>>(center, nbr, a, out);
}